// Round 2
// baseline (346.104 us; speedup 1.0000x reference)
//
#include <hip/hip_runtime.h>
#include <stdint.h>

// Problem constants (fixed instance)
#define B_    32
#define S_    4096
#define E_    256
#define P_    256
#define M_    16
#define G_    (B_*P_)      // 8192 groups
#define NSLOT (G_*M_)      // 131072 slots (== tokens)
#define ROWS  128          // 8 groups * 16 slots per workgroup
#define NWG   (G_/8)       // 1024 workgroups

typedef float fv4 __attribute__((ext_vector_type(4)));
typedef int   iv4 __attribute__((ext_vector_type(4)));
typedef int   iv2 __attribute__((ext_vector_type(2)));
typedef __bf16 bv8 __attribute__((ext_vector_type(8)));
typedef short  sv4 __attribute__((ext_vector_type(4)));

__device__ __forceinline__ uint32_t bf16rne(float f) {
  uint32_t u = __builtin_bit_cast(uint32_t, f);
  u += 0x7fffu + ((u >> 16) & 1u);
  return u >> 16;
}
__device__ __forceinline__ uint32_t pk2(uint32_t lo, uint32_t hi) {
  return (lo & 0xffffu) | (hi << 16);
}
// Builtins (NOT inline asm): the hazard recognizer must see the MFMAs to
// insert mandatory wait-states for VALU-read-after-MFMA-write; inline asm is
// opaque to it and produced undefined reads (round-1 NaN).
__device__ __forceinline__ void mfma32(fv4& d, iv4 a, iv4 b) {
  d = __builtin_amdgcn_mfma_f32_16x16x32_bf16(
        __builtin_bit_cast(bv8, a), __builtin_bit_cast(bv8, b), d, 0, 0, 0);
}
__device__ __forceinline__ void mfma16(fv4& d, iv2 a, iv2 b) {
  d = __builtin_amdgcn_mfma_f32_16x16x16bf16_1k(
        __builtin_bit_cast(sv4, a), __builtin_bit_cast(sv4, b), d, 0, 0, 0);
}

// XOR swizzle: permutes 16B blocks within 128B sub-rows; consistent for all
// aligned accesses >=2B since only byte bits 4-6 are flipped.
#define SWZ(off, row) ((off) ^ (((row) & 7) << 4))

// ---------------- prep kernels ----------------
__global__ void k_init(int* cnt, int* s2t) {
  int i = blockIdx.x * 256 + threadIdx.x;
  if (i < G_) cnt[i] = 0;
  if (i < NSLOT) s2t[i] = -1;
}

__global__ void k_trans(const float* __restrict__ Wq, const float* __restrict__ Wk,
                        const float* __restrict__ Wv, const float* __restrict__ W0,
                        uint16_t* __restrict__ WT) {
  // WT: 4 concatenated [256][256] bf16, WT[w][n][k] = bf16(W[w][k][n])
  int o = blockIdx.x * 256 + threadIdx.x;     // 0..65535
  int wsel = blockIdx.y;
  const float* W = (wsel == 0) ? Wq : (wsel == 1) ? Wk : (wsel == 2) ? Wv : W0;
  int n = o >> 8, k = o & 255;
  WT[(size_t)wsel * 65536 + o] = (uint16_t)bf16rne(W[k * 256 + n]);
}

__global__ void k_rank(const int* __restrict__ pos, int* cnt, int* s2t) {
  int i = blockIdx.x * 256 + threadIdx.x;
  if (i >= B_ * S_) return;
  int p = pos[i];
  if (p < 0 || p >= P_) return;          // invalid -> dropped (stays -1)
  int b = i >> 12;                       // i / S_
  int g = (b << 8) + p;
  int r = atomicAdd(&cnt[g], 1);         // arbitrary slot order: attention is
  if (r < M_) s2t[g * M_ + r] = i;       // permutation-equivariant, so OK
}

// ---------------- fused main kernel ----------------
// 1 WG = 8 groups = 128 rows. 4 waves in a 2x2 (row-half x col-half) grid.
// LDS 128 KiB: [0,64K) X-staging then W-tile; Q/K/V 16K each; ctx 16K.
__global__ __launch_bounds__(256, 1) void k_main(
    const float* __restrict__ emb, const int* __restrict__ s2t,
    const uint16_t* __restrict__ WT, float* __restrict__ out) {
  extern __shared__ char smem[];
  char* XW = smem;             // 64 KiB: X during gather, W tiles afterwards
  char* Qb = smem + 65536;     // 16 KiB  [128][64] bf16, 128B rows, swizzled
  char* Kb = smem + 81920;
  char* Vb = smem + 98304;
  char* Cb = smem + 114688;    // ctx

  const uint16_t* WqT = WT;
  const uint16_t* WkT = WT + 65536;
  const uint16_t* WvT = WT + 131072;
  const uint16_t* W0T = WT + 196608;

  const int tid = threadIdx.x;
  const int l = tid & 63;
  const int w = tid >> 6;           // wave 0..3
  const int lane15 = l & 15;
  const int lq = l >> 4;            // lane quad 0..3
  const int wr = w >> 1, wc = w & 1;
  const int slot0 = blockIdx.x * ROWS;

  // ---- gather: 128 token rows -> bf16 X in LDS (coalesced 1KB row loads) ----
  #pragma unroll 4
  for (int rl = 0; rl < 32; ++rl) {
    int row = w * 32 + rl;
    int t = s2t[slot0 + row];            // wave-uniform
    uint32_t u0 = 0, u1 = 0;
    if (t >= 0) {
      const float4 v = *reinterpret_cast<const float4*>(emb + (size_t)t * E_ + (l << 2));
      u0 = pk2(bf16rne(v.x), bf16rne(v.y));
      u1 = pk2(bf16rne(v.z), bf16rne(v.w));
    }
    iv2 val; val[0] = (int)u0; val[1] = (int)u1;
    *reinterpret_cast<iv2*>(XW + row * 512 + SWZ(l * 8, row)) = val;
  }
  __syncthreads();

  // ---- X A-fragments into registers: 4 m-tiles x 8 k-steps (128 VGPR) ----
  iv4 xf[4][8];
  #pragma unroll
  for (int mt = 0; mt < 4; ++mt) {
    int row = wr * 64 + mt * 16 + lane15;
    #pragma unroll
    for (int ks = 0; ks < 8; ++ks)
      xf[mt][ks] = *reinterpret_cast<const iv4*>(XW + row * 512 + SWZ(ks * 64 + lq * 16, row));
  }
  __syncthreads();   // X region now reusable for weight tiles

  fv4 outacc[4][8];  // 64 rows x 128 cols per wave, persists across chunks
  #pragma unroll
  for (int a = 0; a < 4; ++a)
    #pragma unroll
    for (int b = 0; b < 8; ++b) outacc[a][b] = fv4{0.f, 0.f, 0.f, 0.f};

  for (int hc = 0; hc < 4; ++hc) {       // 4 head-chunks of 64 cols (2 heads)
    const int c0 = hc * 64;

    // ---- Q/K/V projections for this chunk ----
    for (int wgt = 0; wgt < 3; ++wgt) {
      const uint16_t* Wt = (wgt == 0) ? WqT : (wgt == 1) ? WkT : WvT;
      char* dstb = (wgt == 0) ? Qb : (wgt == 1) ? Kb : Vb;
      __syncthreads();                   // previous W readers done
      // stage W^T rows c0..c0+63 (32 KiB) -> XW [64][512B], swizzled
      #pragma unroll
      for (int it = 0; it < 8; ++it) {
        int idx = it * 256 + tid;
        int n = idx >> 5, seg = idx & 31;
        iv4 d = *reinterpret_cast<const iv4*>(
            reinterpret_cast<const char*>(Wt) + (size_t)(c0 + n) * 512 + seg * 16);
        *reinterpret_cast<iv4*>(XW + n * 512 + SWZ(seg * 16, n)) = d;
      }
      __syncthreads();
      fv4 acc[4][2];
      #pragma unroll
      for (int a = 0; a < 4; ++a) { acc[a][0] = fv4{0.f,0.f,0.f,0.f}; acc[a][1] = fv4{0.f,0.f,0.f,0.f}; }
      #pragma unroll
      for (int ks = 0; ks < 8; ++ks) {
        int n0 = wc * 32 + lane15;
        int n1 = n0 + 16;
        iv4 b0 = *reinterpret_cast<const iv4*>(XW + n0 * 512 + SWZ(ks * 64 + lq * 16, n0));
        iv4 b1 = *reinterpret_cast<const iv4*>(XW + n1 * 512 + SWZ(ks * 64 + lq * 16, n1));
        #pragma unroll
        for (int mt = 0; mt < 4; ++mt) {
          mfma32(acc[mt][0], xf[mt][ks], b0);
          mfma32(acc[mt][1], xf[mt][ks], b1);
        }
      }
      // write bf16 result [128][64]
      #pragma unroll
      for (int mt = 0; mt < 4; ++mt)
        #pragma unroll
        for (int nt = 0; nt < 2; ++nt)
          #pragma unroll
          for (int r = 0; r < 4; ++r) {
            int row = wr * 64 + mt * 16 + lq * 4 + r;
            int col = wc * 32 + nt * 16 + lane15;
            *reinterpret_cast<uint16_t*>(dstb + row * 128 + SWZ(col * 2, row)) =
                (uint16_t)bf16rne(acc[mt][nt][r]);
          }
    }
    __syncthreads();   // Q/K/V visible to all waves

    // ---- attention: 16 (group,head) pairs, 4 per wave ----
    #pragma unroll
    for (int pp = 0; pp < 4; ++pp) {
      int pair = w * 4 + pp;
      int g = pair >> 1, hh = pair & 1;
      int rowb = g * 16;
      int frow = rowb + lane15;
      // swapped QK^T: A = K (row=key), B = Q read row-major == Q^T B-layout
      iv4 kf = *reinterpret_cast<const iv4*>(Kb + frow * 128 + SWZ(hh * 64 + lq * 16, frow));
      iv4 qf = *reinterpret_cast<const iv4*>(Qb + frow * 128 + SWZ(hh * 64 + lq * 16, frow));
      fv4 s = fv4{0.f, 0.f, 0.f, 0.f};
      mfma32(s, kf, qf);                 // s[r] = S^T[key=lq*4+r][query=lane15]
      float mx = fmaxf(fmaxf(s[0], s[1]), fmaxf(s[2], s[3]));
      mx = fmaxf(mx, __shfl_xor(mx, 16));
      mx = fmaxf(mx, __shfl_xor(mx, 32));
      const float Cc = 0.25503373f;      // log2(e)/sqrt(32)
      float e0 = exp2f((s[0] - mx) * Cc), e1 = exp2f((s[1] - mx) * Cc);
      float e2 = exp2f((s[2] - mx) * Cc), e3 = exp2f((s[3] - mx) * Cc);
      float sum = e0 + e1 + e2 + e3;
      sum += __shfl_xor(sum, 16);
      sum += __shfl_xor(sum, 32);
      float inv = 1.0f / sum;
      iv2 pa; pa[0] = (int)pk2(bf16rne(e0 * inv), bf16rne(e1 * inv));
              pa[1] = (int)pk2(bf16rne(e2 * inv), bf16rne(e3 * inv));
      // PV: ctx[m][dv] via 16x16x16; P acc layout == A layout (no shuffles)
      #pragma unroll
      for (int dvt = 0; dvt < 2; ++dvt) {
        int col = hh * 32 + dvt * 16 + lane15;
        int r0 = rowb + lq * 4;
        uint32_t v0 = *reinterpret_cast<const uint16_t*>(Vb + (r0 + 0) * 128 + SWZ(col * 2, r0 + 0));
        uint32_t v1 = *reinterpret_cast<const uint16_t*>(Vb + (r0 + 1) * 128 + SWZ(col * 2, r0 + 1));
        uint32_t v2 = *reinterpret_cast<const uint16_t*>(Vb + (r0 + 2) * 128 + SWZ(col * 2, r0 + 2));
        uint32_t v3 = *reinterpret_cast<const uint16_t*>(Vb + (r0 + 3) * 128 + SWZ(col * 2, r0 + 3));
        iv2 bv; bv[0] = (int)pk2(v0, v1); bv[1] = (int)pk2(v2, v3);
        fv4 cacc = fv4{0.f, 0.f, 0.f, 0.f};
        mfma16(cacc, pa, bv);
        #pragma unroll
        for (int r = 0; r < 4; ++r) {
          int row = rowb + lq * 4 + r;
          *reinterpret_cast<uint16_t*>(Cb + row * 128 + SWZ(col * 2, row)) =
              (uint16_t)bf16rne(cacc[r]);
        }
      }
    }
    __syncthreads();   // ctx visible; QKV-proj W readers long done

    // ---- stage W0^T chunk: rows 0..255, k-slice c0..c0+63 -> XW [256][128B] ----
    #pragma unroll
    for (int it = 0; it < 8; ++it) {
      int idx = it * 256 + tid;
      int n = idx >> 3, seg = idx & 7;
      iv4 d = *reinterpret_cast<const iv4*>(
          reinterpret_cast<const char*>(W0T) + (size_t)n * 512 + c0 * 2 + seg * 16);
      *reinterpret_cast<iv4*>(XW + n * 128 + SWZ(seg * 16, n)) = d;
    }
    __syncthreads();

    // ---- out += ctx_chunk @ W0[c0:c0+64, :]  (wave: 64 rows x 128 cols) ----
    #pragma unroll
    for (int ks = 0; ks < 2; ++ks) {
      iv4 af[4];
      #pragma unroll
      for (int mt = 0; mt < 4; ++mt) {
        int row = wr * 64 + mt * 16 + lane15;
        af[mt] = *reinterpret_cast<const iv4*>(Cb + row * 128 + SWZ(ks * 64 + lq * 16, row));
      }
      #pragma unroll
      for (int nt = 0; nt < 8; ++nt) {
        int n = wc * 128 + nt * 16 + lane15;
        iv4 bfg = *reinterpret_cast<const iv4*>(XW + n * 128 + SWZ(ks * 64 + lq * 16, n));
        #pragma unroll
        for (int mt = 0; mt < 4; ++mt) mfma32(outacc[mt][nt], af[mt], bfg);
      }
    }
  } // hc

  // ---- scatter out (fp32, 64B segments per 16-lane group) ----
  #pragma unroll
  for (int mt = 0; mt < 4; ++mt) {
    int rb = wr * 64 + mt * 16 + lq * 4;
    int t0 = s2t[slot0 + rb + 0];
    int t1 = s2t[slot0 + rb + 1];
    int t2 = s2t[slot0 + rb + 2];
    int t3 = s2t[slot0 + rb + 3];
    #pragma unroll
    for (int nt = 0; nt < 8; ++nt) {
      int col = wc * 128 + nt * 16 + lane15;
      if (t0 >= 0) out[(size_t)t0 * E_ + col] = outacc[mt][nt][0];
      if (t1 >= 0) out[(size_t)t1 * E_ + col] = outacc[mt][nt][1];
      if (t2 >= 0) out[(size_t)t2 * E_ + col] = outacc[mt][nt][2];
      if (t3 >= 0) out[(size_t)t3 * E_ + col] = outacc[mt][nt][3];
    }
  }
}

extern "C" void kernel_launch(void* const* d_in, const int* in_sizes, int n_in,
                              void* d_out, int out_size, void* d_ws, size_t ws_size,
                              hipStream_t stream) {
  (void)in_sizes; (void)n_in; (void)out_size; (void)ws_size;
  const float* emb = (const float*)d_in[0];
  const float* Wq  = (const float*)d_in[1];
  const float* Wk  = (const float*)d_in[2];
  const float* Wv  = (const float*)d_in[3];
  const float* W0  = (const float*)d_in[4];
  const int*   pos = (const int*)d_in[5];
  float* out = (float*)d_out;

  // ws layout: cnt 32KB | s2t 512KB | WT(4x bf16 256x256) 512KB
  int* cnt = (int*)d_ws;
  int* s2t = (int*)((char*)d_ws + 32768);
  uint16_t* WT = (uint16_t*)((char*)d_ws + 32768 + 524288);

  (void)hipFuncSetAttribute(reinterpret_cast<const void*>(k_main),
                            hipFuncAttributeMaxDynamicSharedMemorySize, 131072);

  k_init <<<512, 256, 0, stream>>>(cnt, s2t);
  k_trans<<<dim3(256, 4), 256, 0, stream>>>(Wq, Wk, Wv, W0, WT);
  k_rank <<<512, 256, 0, stream>>>(pos, cnt, s2t);
  k_main <<<NWG, 256, 131072, stream>>>(emb, s2t, WT, out);
}